// Round 8
// baseline (293.136 us; speedup 1.0000x reference)
//
#include <hip/hip_runtime.h>
#include <cstdint>
#include <cstddef>

typedef unsigned short u16;
typedef __attribute__((ext_vector_type(8))) __bf16 bf16x8;
typedef __attribute__((ext_vector_type(4))) float f32x4;
typedef __attribute__((ext_vector_type(16))) float f32x16;
typedef __attribute__((ext_vector_type(2))) uint32_t u32x2;
typedef __attribute__((ext_vector_type(4))) float float4v;

#define BATCH 4
#define S_LEN 2048
#define DMODEL 1024
#define NHEAD 16
#define HDIM 64
#define MROWS (BATCH * S_LEN)   // 8192
#define LOG2E 1.4426950408889634f
#define SC_L (0.125f * LOG2E)   // 1/sqrt(64) * log2(e)

__device__ __forceinline__ u16 f2bf(float f) {
  uint32_t u = __float_as_uint(f);
  u += 0x7fffu + ((u >> 16) & 1u);   // RNE
  return (u16)(u >> 16);
}

#if __has_builtin(__builtin_amdgcn_cvt_pk_bf16_f32)
__device__ __forceinline__ uint32_t packbf2(float a, float b) {
  auto t = __builtin_amdgcn_cvt_pk_bf16_f32(a, b);
  uint32_t u;
  __builtin_memcpy(&u, &t, 4);
  return u;
}
#else
__device__ __forceinline__ uint32_t packbf2(float a, float b) {
  uint32_t ua = __float_as_uint(a) + 0x8000u;
  uint32_t ub = __float_as_uint(b) + 0x8000u;
  return (ub & 0xFFFF0000u) | (ua >> 16);
}
#endif

#if __has_builtin(__builtin_amdgcn_exp2f)
#define EXP2(x) __builtin_amdgcn_exp2f(x)
#else
#define EXP2(x) exp2f(x)
#endif

typedef __attribute__((address_space(1))) void gvoid_t;
typedef __attribute__((address_space(3))) void svoid_t;
__device__ __forceinline__ void gl_lds16(const void* g, void* s) {
  __builtin_amdgcn_global_load_lds((gvoid_t*)g, (svoid_t*)s, 16, 0, 0);
}

// ---------------- fused prep: x cvt (8192 blks) + W transpose/cvt (4096 blks)
//                  + mask*LOG2E (32 blks) ----------------
// R7 lesson: folding LOG2E into attn cost 5.6us (attn is VALU-bound); the
// pre-scale lives here instead. Dispatch count stays 4.
#define NB_CVT (MROWS * DMODEL / 4 / 256)   // 8192
#define NB_W   4096
__global__ __launch_bounds__(256) void prep_kernel(const float4v* __restrict__ x,
                                                   u32x2* __restrict__ xb,
                                                   const float* __restrict__ W0,
                                                   const float* __restrict__ W1,
                                                   const float* __restrict__ W2,
                                                   const float* __restrict__ W3,
                                                   u16* __restrict__ Wall,
                                                   const float* __restrict__ mask,
                                                   float* __restrict__ mL) {
  __shared__ float tile[32][33];
  const int bid = blockIdx.x;
  const int tid = threadIdx.x;
  if (bid < NB_CVT) {
    const int i = bid * 256 + tid;
    float4v v = x[i];
    u32x2 o;
    o.x = packbf2(v.x, v.y);
    o.y = packbf2(v.z, v.w);
    xb[i] = o;
    return;
  }
  if (bid >= NB_CVT + NB_W) {   // mask * log2e
    const int i = (bid - NB_CVT - NB_W) * 256 + tid;
    mL[i] = mask[i] * LOG2E;
    return;
  }
  const int r = bid - NB_CVT;        // 0..4095
  const int z = r >> 10;             // weight index
  const int rem = r & 1023;
  const float* W = (z == 0) ? W0 : (z == 1) ? W1 : (z == 2) ? W2 : W3;
  u16* Wt = Wall + (size_t)z * DMODEL * DMODEL;
  const int n0 = (rem & 31) * 32, k0 = (rem >> 5) * 32;
  const int xx = tid & 31, y = tid >> 5;   // flattened (32,8)
  for (int yy = y; yy < 32; yy += 8)
    tile[yy][xx] = W[(size_t)(k0 + yy) * DMODEL + n0 + xx];
  __syncthreads();
  for (int yy = y; yy < 32; yy += 8)
    Wt[(size_t)(n0 + yy) * DMODEL + k0 + xx] = f2bf(tile[xx][yy]);
}

// ---------------- m97-style GEMM, fully-unrolled 3-buffer counted-vmcnt pipeline ----------------
// MODE 0: fused QKV, N=3072. seg 0/1 -> Q/K head layout [B,NH,S,HD];
//         seg 2 -> V written TRANSPOSED [B,NH,HD,S] (feeds attention directly).
// MODE 1: N=1024, fp32 out row-major.
// Pipelining ledger on this structure:
//   R5 2-phase + __syncthreads: 106.5us (drains just-issued loads).
//   R6 T4 3-buf counted-vmcnt, RUNTIME buf indices: 96us. Mechanism worked
//     (MfmaUtil 19.9->22.7, correctness clean) but VALUBusy 12->43.5%:
//     runtime indices defeat LDS/global address folding.
//   R8 (this): SAME R6 schedule, loop fully unrolled -> r%3 is a
//     compile-time constant -> every ds_read/gl_lds address is one
//     loop-invariant base + literal offset. R6's latency win w/o its VALU cost.
// Waits: steady-state vmcnt(4) leaves the newest STAGE (tile t+2, 4 loads)
// in flight across the barrier; each wave drains ITS OWN tile t+1 loads
// before the barrier, so post-barrier all waves' t+1 data is in LDS.
// NOTE: NO XCD swizzle (R1: chunked swizzle -> FETCH 137MB, +17us).
template <int MODE>
__global__ __launch_bounds__(256) void gemm128(const u16* __restrict__ A,
                                               const u16* __restrict__ Bt,
                                               const float* __restrict__ b0,
                                               const float* __restrict__ b1,
                                               const float* __restrict__ b2,
                                               void* __restrict__ o0,
                                               void* __restrict__ o1,
                                               void* __restrict__ o2) {
  __shared__ u16 As[3][128 * 32];
  __shared__ u16 Bs[3][128 * 32];
  const int tid = threadIdx.x;
  const int wid = tid >> 6;
  const int lane = tid & 63;
  const int l16 = lane & 15;
  const int g4 = lane >> 4;
  const int m0 = blockIdx.x * 128;
  const int n0 = blockIdx.y * 128;
  const int wm = (wid & 1) * 64;
  const int wn = (wid >> 1) * 64;

  const int srow = tid >> 2;
  const int sk = (tid & 3) * 8;
  const u16* gA = A + (size_t)(m0 + srow) * DMODEL + sk;
  const u16* gB = Bt + (size_t)(n0 + srow) * DMODEL + sk;

  f32x4 acc[4][4];
#pragma unroll
  for (int i = 0; i < 4; ++i)
#pragma unroll
    for (int j = 0; j < 4; ++j) acc[i][j] = (f32x4){0.f, 0.f, 0.f, 0.f};

  // stage one BK=32 tile (A+B) into buffer c (4 gl_lds / wave); c,t literal
#define STAGE_T(c, t)                                                   \
  {                                                                     \
    char* sa = (char*)As + (c) * 8192 + wid * 1024;                     \
    char* sb = (char*)Bs + (c) * 8192 + wid * 1024;                     \
    gl_lds16(gA + (t) * 32, sa);                                        \
    gl_lds16(gA + (size_t)64 * DMODEL + (t) * 32, sa + 4096);           \
    gl_lds16(gB + (t) * 32, sb);                                        \
    gl_lds16(gB + (size_t)64 * DMODEL + (t) * 32, sb + 4096);           \
  }

  const int NT = DMODEL / 32;   // 32 rounds

  STAGE_T(0, 0)
  STAGE_T(1, 1)
  asm volatile("s_waitcnt vmcnt(4)" ::: "memory");
  __builtin_amdgcn_sched_barrier(0);
  __builtin_amdgcn_s_barrier();
  __builtin_amdgcn_sched_barrier(0);

#pragma unroll
  for (int r = 0; r < 32; ++r) {
    const int c = r % 3;
    if (r + 2 < NT) {
      const int c2 = (r + 2) % 3;
      STAGE_T(c2, r + 2)
    }

    const u16* Ab = &As[c][0];
    const u16* Bb = &Bs[c][0];
    bf16x8 af[4], bfr[4];
#pragma unroll
    for (int i = 0; i < 4; ++i)
      af[i] = *(const bf16x8*)(Ab + (wm + i * 16 + l16) * 32 + g4 * 8);
#pragma unroll
    for (int j = 0; j < 4; ++j)
      bfr[j] = *(const bf16x8*)(Bb + (wn + j * 16 + l16) * 32 + g4 * 8);
#pragma unroll
    for (int i = 0; i < 4; ++i)
#pragma unroll
      for (int j = 0; j < 4; ++j)
        acc[i][j] = __builtin_amdgcn_mfma_f32_16x16x32_bf16(af[i], bfr[j],
                                                            acc[i][j], 0, 0, 0);

    if (r + 1 < NT) {
      if (r + 2 < NT)
        asm volatile("s_waitcnt vmcnt(4)" ::: "memory");
      else
        asm volatile("s_waitcnt vmcnt(0)" ::: "memory");
      __builtin_amdgcn_sched_barrier(0);
      __builtin_amdgcn_s_barrier();
      __builtin_amdgcn_sched_barrier(0);
    }
  }
#undef STAGE_T

  const int seg = n0 >> 10;   // wave-uniform
  const float* bp = (MODE == 1 || seg == 0) ? b0 : (seg == 1 ? b1 : b2);
  void* op = (MODE == 1 || seg == 0) ? o0 : (seg == 1 ? o1 : o2);

#pragma unroll
  for (int i = 0; i < 4; ++i) {
#pragma unroll
    for (int j = 0; j < 4; ++j) {
      const int coll = n0 + wn + j * 16 + l16;
      const int cseg = coll & 1023;
      const float bval = bp[cseg];
#pragma unroll
      for (int r = 0; r < 4; ++r) {
        const int rowg = m0 + wm + i * 16 + g4 * 4 + r;
        const float v = acc[i][j][r] + bval;
        if (MODE == 0) {
          const int b = rowg >> 11, s = rowg & (S_LEN - 1);
          const int h = cseg >> 6, d = cseg & (HDIM - 1);
          if (seg == 2) {   // V transposed: [B,NH,HD,S]
            ((u16*)op)[(((size_t)(b * NHEAD + h) * HDIM + d) << 11) + s] = f2bf(v);
          } else {
            ((u16*)op)[((size_t)((b * NHEAD + h) * S_LEN + s) << 6) + d] = f2bf(v);
          }
        } else {
          ((float*)op)[(size_t)rowg * DMODEL + cseg] = v;
        }
      }
    }
  }
}

// ---------------- flash attention v4 (measured best: 94.2us, restored byte-exact) ----------------
// 64 q per wave, 256 q per block. P stays in registers: the S^T C-layout,
// packed pairwise, is a valid A-fragment under key-permutation
// pi = [0,1,2,3,8,9,10,11 | 4,5,6,7,12,13,14,15]; V is staged into LDS with
// pi applied so PV B-fragments are contiguous b128 reads.
// Ledger: R1 dbuf/T14/T5 neutral; R2 reg-cap spill 3x; R4 32q/wave 107us;
// R7 in-loop LOG2E fold +5.6us (VALU-bound: VALUBusy 47 > MfmaUtil 38,
// exp2 dominates). Takes pre-scaled maskL. Do not add VALU work here.
__global__ __launch_bounds__(256, 2) void attn4_kernel(const u16* __restrict__ Q,
                                                       const u16* __restrict__ K,
                                                       const u16* __restrict__ Vt,
                                                       const float* __restrict__ maskL,
                                                       u16* __restrict__ ctx) {
  __shared__ u16 Ks[64 * 72];   // [key][d]
  __shared__ u16 Vs[64 * 72];   // [d][key'] (pi-permuted keys)

  const int tid = threadIdx.x;
  const int wid = tid >> 6;
  const int lane = tid & 63;
  const int l32 = lane & 31;
  const int hi = lane >> 5;
  // XCD swizzle: 512 blocks, 8 q-blocks/head; 64 consecutive nf per XCD = 8 heads.
  const int flat = blockIdx.y * gridDim.x + blockIdx.x;
  const int nf = (flat & 7) * 64 + (flat >> 3);
  const int bx = nf & 7;
  const int bh = nf >> 3;
  const int b = bh >> 4;
  const int h = bh & 15;
  const int qw0 = bx * 256 + wid * 64;

  // Q B-fragments for both q-halves
  const u16* Qbase = Q + (size_t)bh * S_LEN * HDIM;
  bf16x8 aq[2][4];
#pragma unroll
  for (int qh = 0; qh < 2; ++qh)
#pragma unroll
    for (int c = 0; c < 4; ++c)
      aq[qh][c] = *(const bf16x8*)(Qbase + (size_t)(qw0 + qh * 32 + l32) * HDIM +
                                   c * 16 + hi * 8);

  union { u16 s[8]; bf16x8 v; } onesu;
#pragma unroll
  for (int i = 0; i < 8; ++i) onesu.s[i] = 0x3F80;
  const bf16x8 onesv = onesu.v;

  const f32x16 z16 = {};
  f32x16 oacc[2][2] = {};   // [qh][dh]
  f32x16 lacc[2] = {};      // [qh]

  const int srow = tid >> 3;           // 0..31
  const int scol = (tid & 7) * 8;      // key offset for staging
  const int keyg = scol >> 4;          // 16-key group
  const int todd = (scol >> 3) & 1;
  const int vkb = keyg * 16 + todd * 4;  // pi-permuted base for V staging
  const u16* Kg = K + (size_t)bh * S_LEN * HDIM + (size_t)srow * HDIM + scol;
  const u16* Vg = Vt + (size_t)bh * HDIM * S_LEN + (size_t)srow * S_LEN + scol;
  const float* mrow = maskL + (size_t)b * S_LEN;

  for (int kt = 0; kt < S_LEN; kt += 64) {
    bf16x8 kv0 = *(const bf16x8*)(Kg + (size_t)kt * HDIM);
    bf16x8 kv1 = *(const bf16x8*)(Kg + (size_t)(kt + 32) * HDIM);
    union { bf16x8 v; uint32_t u[4]; } vv0, vv1;
    vv0.v = *(const bf16x8*)(Vg + kt);
    vv1.v = *(const bf16x8*)(Vg + (size_t)32 * S_LEN + kt);
    __syncthreads();
    *(bf16x8*)(Ks + srow * 72 + scol) = kv0;
    *(bf16x8*)(Ks + (srow + 32) * 72 + scol) = kv1;
    // V with pi: keys {base..base+3} -> key' vkb, {base+4..7} -> key' vkb+8
    *(u32x2*)(Vs + srow * 72 + vkb) = (u32x2){vv0.u[0], vv0.u[1]};
    *(u32x2*)(Vs + srow * 72 + vkb + 8) = (u32x2){vv0.u[2], vv0.u[3]};
    *(u32x2*)(Vs + (srow + 32) * 72 + vkb) = (u32x2){vv1.u[0], vv1.u[1]};
    *(u32x2*)(Vs + (srow + 32) * 72 + vkb + 8) = (u32x2){vv1.u[2], vv1.u[3]};
    __syncthreads();

    uint32_t P[2][2][8];   // [T][qh][dword]
#pragma unroll
    for (int T = 0; T < 2; ++T) {
      bf16x8 kf[4];
#pragma unroll
      for (int c = 0; c < 4; ++c)
        kf[c] = *(const bf16x8*)(Ks + (T * 32 + l32) * 72 + c * 16 + hi * 8);
      f32x4 m4[4];
#pragma unroll
      for (int tq = 0; tq < 4; ++tq)
        m4[tq] = *(const f32x4*)(mrow + kt + T * 32 + tq * 8 + hi * 4);
#pragma unroll
      for (int qh = 0; qh < 2; ++qh) {
        f32x16 s = __builtin_amdgcn_mfma_f32_32x32x16_bf16(kf[0], aq[qh][0], z16, 0, 0, 0);
#pragma unroll
        for (int c = 1; c < 4; ++c)
          s = __builtin_amdgcn_mfma_f32_32x32x16_bf16(kf[c], aq[qh][c], s, 0, 0, 0);
#pragma unroll
        for (int tq = 0; tq < 4; ++tq) {
          float p0 = EXP2(fmaf(s[tq * 4 + 0], SC_L, m4[tq][0]));
          float p1 = EXP2(fmaf(s[tq * 4 + 1], SC_L, m4[tq][1]));
          float p2 = EXP2(fmaf(s[tq * 4 + 2], SC_L, m4[tq][2]));
          float p3 = EXP2(fmaf(s[tq * 4 + 3], SC_L, m4[tq][3]));
          P[T][qh][tq * 2] = packbf2(p0, p1);
          P[T][qh][tq * 2 + 1] = packbf2(p2, p3);
        }
      }
    }

    // PV + l: A = in-register P fragments, B = pi-permuted V from LDS
#pragma unroll
    for (int c = 0; c < 4; ++c) {
      const int T = c >> 1, half = c & 1;
      bf16x8 vf[2];
#pragma unroll
      for (int dh = 0; dh < 2; ++dh)
        vf[dh] = *(const bf16x8*)(Vs + (dh * 32 + l32) * 72 + c * 16 + hi * 8);
#pragma unroll
      for (int qh = 0; qh < 2; ++qh) {
        union { uint32_t u[4]; bf16x8 v; } pf;
#pragma unroll
        for (int e = 0; e < 4; ++e) pf.u[e] = P[T][qh][half * 4 + e];
        oacc[qh][0] = __builtin_amdgcn_mfma_f32_32x32x16_bf16(pf.v, vf[0], oacc[qh][0], 0, 0, 0);
        oacc[qh][1] = __builtin_amdgcn_mfma_f32_32x32x16_bf16(pf.v, vf[1], oacc[qh][1], 0, 0, 0);
        lacc[qh] = __builtin_amdgcn_mfma_f32_32x32x16_bf16(pf.v, onesv, lacc[qh], 0, 0, 0);
      }
    }
  }

  // epilogue: ctx [B,S,NH,HD]
#pragma unroll
  for (int qh = 0; qh < 2; ++qh) {
#pragma unroll
    for (int reg = 0; reg < 16; ++reg) {
      const int q = qw0 + qh * 32 + (reg & 3) + 8 * (reg >> 2) + 4 * hi;
      const float inv = 1.0f / lacc[qh][reg];
      u16* cp = ctx + ((size_t)(b * S_LEN + q) * NHEAD + h) * HDIM;
      cp[l32] = f2bf(oacc[qh][0][reg] * inv);
      cp[32 + l32] = f2bf(oacc[qh][1][reg] * inv);
    }
  }
}

extern "C" void kernel_launch(void* const* d_in, const int* in_sizes, int n_in,
                              void* d_out, int out_size, void* d_ws, size_t ws_size,
                              hipStream_t stream) {
  const float* x = (const float*)d_in[0];
  const float* mask = (const float*)d_in[1];
  const float* Wq = (const float*)d_in[2];
  const float* bq = (const float*)d_in[3];
  const float* Wk = (const float*)d_in[4];
  const float* bk = (const float*)d_in[5];
  const float* Wv = (const float*)d_in[6];
  const float* bv = (const float*)d_in[7];
  const float* Wo = (const float*)d_in[8];
  const float* bo = (const float*)d_in[9];
  float* out = (float*)d_out;

  char* ws = (char*)d_ws;
  size_t off = 0;
  u16* xb = (u16*)(ws + off);    off += (size_t)MROWS * DMODEL * 2;
  u16* wall = (u16*)(ws + off);  off += (size_t)4 * DMODEL * DMODEL * 2;  // Wq,Wk,Wv,Wo transposed
  u16* Qh = (u16*)(ws + off);    off += (size_t)MROWS * DMODEL * 2;   // [B,NH,S,HD]
  u16* Kh = (u16*)(ws + off);    off += (size_t)MROWS * DMODEL * 2;
  u16* Vtb = (u16*)(ws + off);   off += (size_t)MROWS * DMODEL * 2;   // [B,NH,HD,S]
  u16* ctxb = (u16*)(ws + off);  off += (size_t)MROWS * DMODEL * 2;   // [B,S,D]
  float* mL = (float*)(ws + off); off += (size_t)BATCH * S_LEN * 4;
  (void)ws_size; (void)in_sizes; (void)n_in; (void)out_size;

  prep_kernel<<<dim3(NB_CVT + NB_W + BATCH * S_LEN / 256), dim3(256), 0, stream>>>(
      (const float4v*)x, (u32x2*)xb, Wq, Wk, Wv, Wo, wall, mask, mL);

  // fused QKV: N = 3072; V written transposed
  gemm128<0><<<dim3(MROWS / 128, 3 * DMODEL / 128), dim3(256), 0, stream>>>(
      xb, wall, bq, bk, bv, (void*)Qh, (void*)Kh, (void*)Vtb);

  attn4_kernel<<<dim3(S_LEN / 256, BATCH * NHEAD), dim3(256), 0, stream>>>(Qh, Kh, Vtb, mL, ctxb);

  gemm128<1><<<dim3(MROWS / 128, DMODEL / 128), dim3(256), 0, stream>>>(
      ctxb, wall + (size_t)3 * DMODEL * DMODEL, bo, bo, bo, (void*)out, (void*)out, (void*)out);
}

// Round 9
// 289.377 us; speedup vs baseline: 1.0130x; 1.0130x over previous
//
#include <hip/hip_runtime.h>
#include <cstdint>
#include <cstddef>

typedef unsigned short u16;
typedef __attribute__((ext_vector_type(8))) __bf16 bf16x8;
typedef __attribute__((ext_vector_type(4))) float f32x4;
typedef __attribute__((ext_vector_type(16))) float f32x16;
typedef __attribute__((ext_vector_type(2))) uint32_t u32x2;
typedef __attribute__((ext_vector_type(4))) float float4v;

#define BATCH 4
#define S_LEN 2048
#define DMODEL 1024
#define NHEAD 16
#define HDIM 64
#define MROWS (BATCH * S_LEN)   // 8192
#define LOG2E 1.4426950408889634f
#define SC_L (0.125f * LOG2E)   // 1/sqrt(64) * log2(e)

__device__ __forceinline__ u16 f2bf(float f) {
  uint32_t u = __float_as_uint(f);
  u += 0x7fffu + ((u >> 16) & 1u);   // RNE
  return (u16)(u >> 16);
}

#if __has_builtin(__builtin_amdgcn_cvt_pk_bf16_f32)
__device__ __forceinline__ uint32_t packbf2(float a, float b) {
  auto t = __builtin_amdgcn_cvt_pk_bf16_f32(a, b);
  uint32_t u;
  __builtin_memcpy(&u, &t, 4);
  return u;
}
#else
__device__ __forceinline__ uint32_t packbf2(float a, float b) {
  uint32_t ua = __float_as_uint(a) + 0x8000u;
  uint32_t ub = __float_as_uint(b) + 0x8000u;
  return (ub & 0xFFFF0000u) | (ua >> 16);
}
#endif

#if __has_builtin(__builtin_amdgcn_exp2f)
#define EXP2(x) __builtin_amdgcn_exp2f(x)
#else
#define EXP2(x) exp2f(x)
#endif

typedef __attribute__((address_space(1))) void gvoid_t;
typedef __attribute__((address_space(3))) void svoid_t;
__device__ __forceinline__ void gl_lds16(const void* g, void* s) {
  __builtin_amdgcn_global_load_lds((gvoid_t*)g, (svoid_t*)s, 16, 0, 0);
}

// ---------------- fused prep: x cvt (8192 blks) + W transpose/cvt (4096 blks)
//                  + mask*LOG2E (32 blks) ----------------
// R7 lesson: folding LOG2E into attn cost 5.6us (attn is MFMA/latency-bound
// with VALU on the softmax path); the pre-scale lives here instead.
#define NB_CVT (MROWS * DMODEL / 4 / 256)   // 8192
#define NB_W   4096
__global__ __launch_bounds__(256) void prep_kernel(const float4v* __restrict__ x,
                                                   u32x2* __restrict__ xb,
                                                   const float* __restrict__ W0,
                                                   const float* __restrict__ W1,
                                                   const float* __restrict__ W2,
                                                   const float* __restrict__ W3,
                                                   u16* __restrict__ Wall,
                                                   const float* __restrict__ mask,
                                                   float* __restrict__ mL) {
  __shared__ float tile[32][33];
  const int bid = blockIdx.x;
  const int tid = threadIdx.x;
  if (bid < NB_CVT) {
    const int i = bid * 256 + tid;
    float4v v = x[i];
    u32x2 o;
    o.x = packbf2(v.x, v.y);
    o.y = packbf2(v.z, v.w);
    xb[i] = o;
    return;
  }
  if (bid >= NB_CVT + NB_W) {   // mask * log2e
    const int i = (bid - NB_CVT - NB_W) * 256 + tid;
    mL[i] = mask[i] * LOG2E;
    return;
  }
  const int r = bid - NB_CVT;        // 0..4095
  const int z = r >> 10;             // weight index
  const int rem = r & 1023;
  const float* W = (z == 0) ? W0 : (z == 1) ? W1 : (z == 2) ? W2 : W3;
  u16* Wt = Wall + (size_t)z * DMODEL * DMODEL;
  const int n0 = (rem & 31) * 32, k0 = (rem >> 5) * 32;
  const int xx = tid & 31, y = tid >> 5;   // flattened (32,8)
  for (int yy = y; yy < 32; yy += 8)
    tile[yy][xx] = W[(size_t)(k0 + yy) * DMODEL + n0 + xx];
  __syncthreads();
  for (int yy = y; yy < 32; yy += 8)
    Wt[(size_t)(n0 + yy) * DMODEL + k0 + xx] = f2bf(tile[xx][yy]);
}

// ---------------- m97-style GEMM, 2 K-subtiles per barrier round (R3, measured best) ----------------
// MODE 0: fused QKV, N=3072. seg 0/1 -> Q/K head layout [B,NH,S,HD];
//         seg 2 -> V written TRANSPOSED [B,NH,HD,S] (feeds attention directly).
// MODE 1: N=1024, fp32 out row-major.
// Pipelining ledger on this structure - CLOSED, serial wins:
//   R3 serial 2-subtile (this): best.
//   R5 2-phase + __syncthreads: +~20us (drains just-issued loads).
//   R6 T4 counted-vmcnt, runtime idx: +~10us (VALU addr overhead).
//   R8 T4 counted-vmcnt, fully unrolled static idx: +7.4us vs serial.
// The m97-structure ceiling is structural (guide: source-level pipelining
// neutral/worse); only a full 8-phase 256^2 template rewrite goes past it.
// NOTE: NO XCD swizzle (R1: chunked swizzle -> FETCH 137MB, +17us).
template <int MODE>
__global__ __launch_bounds__(256) void gemm128(const u16* __restrict__ A,
                                               const u16* __restrict__ Bt,
                                               const float* __restrict__ b0,
                                               const float* __restrict__ b1,
                                               const float* __restrict__ b2,
                                               void* __restrict__ o0,
                                               void* __restrict__ o1,
                                               void* __restrict__ o2) {
  __shared__ u16 As[2 * 128 * 32];   // [subtile][row][k32]
  __shared__ u16 Bs[2 * 128 * 32];
  const int tid = threadIdx.x;
  const int wid = tid >> 6;
  const int lane = tid & 63;
  const int l16 = lane & 15;
  const int g4 = lane >> 4;
  const int m0 = blockIdx.x * 128;
  const int n0 = blockIdx.y * 128;
  const int wm = (wid & 1) * 64;
  const int wn = (wid >> 1) * 64;

  const int srow = tid >> 2;
  const int sk = (tid & 3) * 8;
  const u16* gA = A + (size_t)(m0 + srow) * DMODEL + sk;
  const u16* gB = Bt + (size_t)(n0 + srow) * DMODEL + sk;
  char* sA = (char*)As + wid * 1024;
  char* sB = (char*)Bs + wid * 1024;

  f32x4 acc[4][4];
#pragma unroll
  for (int i = 0; i < 4; ++i)
#pragma unroll
    for (int j = 0; j < 4; ++j) acc[i][j] = (f32x4){0.f, 0.f, 0.f, 0.f};

  for (int k0 = 0; k0 < DMODEL; k0 += 64) {
    __syncthreads();
    // subtile 0: K = k0..k0+31
    gl_lds16(gA + k0, sA);
    gl_lds16(gA + (size_t)64 * DMODEL + k0, sA + 4096);
    gl_lds16(gB + k0, sB);
    gl_lds16(gB + (size_t)64 * DMODEL + k0, sB + 4096);
    // subtile 1: K = k0+32..k0+63 (second 8KB tile, identical layout)
    gl_lds16(gA + k0 + 32, sA + 8192);
    gl_lds16(gA + (size_t)64 * DMODEL + k0 + 32, sA + 12288);
    gl_lds16(gB + k0 + 32, sB + 8192);
    gl_lds16(gB + (size_t)64 * DMODEL + k0 + 32, sB + 12288);
    __syncthreads();

#pragma unroll
    for (int kk = 0; kk < 2; ++kk) {
      const u16* Ab = As + kk * 4096;
      const u16* Bb = Bs + kk * 4096;
      bf16x8 af[4], bfr[4];
#pragma unroll
      for (int i = 0; i < 4; ++i)
        af[i] = *(const bf16x8*)(Ab + (wm + i * 16 + l16) * 32 + g4 * 8);
#pragma unroll
      for (int j = 0; j < 4; ++j)
        bfr[j] = *(const bf16x8*)(Bb + (wn + j * 16 + l16) * 32 + g4 * 8);
#pragma unroll
      for (int i = 0; i < 4; ++i)
#pragma unroll
        for (int j = 0; j < 4; ++j)
          acc[i][j] = __builtin_amdgcn_mfma_f32_16x16x32_bf16(af[i], bfr[j],
                                                              acc[i][j], 0, 0, 0);
    }
  }

  const int seg = n0 >> 10;   // wave-uniform
  const float* bp = (MODE == 1 || seg == 0) ? b0 : (seg == 1 ? b1 : b2);
  void* op = (MODE == 1 || seg == 0) ? o0 : (seg == 1 ? o1 : o2);

#pragma unroll
  for (int i = 0; i < 4; ++i) {
#pragma unroll
    for (int j = 0; j < 4; ++j) {
      const int coll = n0 + wn + j * 16 + l16;
      const int cseg = coll & 1023;
      const float bval = bp[cseg];
#pragma unroll
      for (int r = 0; r < 4; ++r) {
        const int rowg = m0 + wm + i * 16 + g4 * 4 + r;
        const float v = acc[i][j][r] + bval;
        if (MODE == 0) {
          const int b = rowg >> 11, s = rowg & (S_LEN - 1);
          const int h = cseg >> 6, d = cseg & (HDIM - 1);
          if (seg == 2) {   // V transposed: [B,NH,HD,S]
            ((u16*)op)[(((size_t)(b * NHEAD + h) * HDIM + d) << 11) + s] = f2bf(v);
          } else {
            ((u16*)op)[((size_t)((b * NHEAD + h) * S_LEN + s) << 6) + d] = f2bf(v);
          }
        } else {
          ((float*)op)[(size_t)rowg * DMODEL + cseg] = v;
        }
      }
    }
  }
}

// ---------------- flash attention v8 ----------------
// Base: attn4 (64 q/wave, 256 q/block, in-register P, pi-permuted V; proven
// 94.2us). Ledger: R1 dbuf/T14/T5 neutral; R2 reg-cap spill 3x; R4 32q/wave
// worse; R7 in-loop VALU add worse.
// R9 change: DELETE the lacc MFMAs (8 of 40 MFMA/tile = 20% of MFMA-pipe
// work computed the softmax denominator P*ones). Counter model: VALUBusy(47)
// includes MFMA issue -> pure VALU ~9%, so attn is MFMA-pipe/latency bound
// with VALU headroom. Replacement: accumulate lsum[qh] += p0..p3 at P-pack
// time (f32, 16 v_add/tile per (T,qh) = 128cyc VALU vs 256cyc MFMA removed).
// Epilogue redistributes l: shfl_xor(32) merges hi-halves (each lane's P
// covers a hi-dependent 16-key subset; union over hi = all keys), then a
// per-reg bpermute moves l[q] from QK^T's q=col layout to oacc's q=row
// layout. One-time cost ~32 bpermutes. Also frees 36 VGPR.
__global__ __launch_bounds__(256, 2) void attn8_kernel(const u16* __restrict__ Q,
                                                       const u16* __restrict__ K,
                                                       const u16* __restrict__ Vt,
                                                       const float* __restrict__ maskL,
                                                       u16* __restrict__ ctx) {
  __shared__ u16 Ks[64 * 72];   // [key][d]
  __shared__ u16 Vs[64 * 72];   // [d][key'] (pi-permuted keys)

  const int tid = threadIdx.x;
  const int wid = tid >> 6;
  const int lane = tid & 63;
  const int l32 = lane & 31;
  const int hi = lane >> 5;
  // XCD swizzle: 512 blocks, 8 q-blocks/head; 64 consecutive nf per XCD = 8 heads.
  const int flat = blockIdx.y * gridDim.x + blockIdx.x;
  const int nf = (flat & 7) * 64 + (flat >> 3);
  const int bx = nf & 7;
  const int bh = nf >> 3;
  const int b = bh >> 4;
  const int h = bh & 15;
  const int qw0 = bx * 256 + wid * 64;

  // Q B-fragments for both q-halves
  const u16* Qbase = Q + (size_t)bh * S_LEN * HDIM;
  bf16x8 aq[2][4];
#pragma unroll
  for (int qh = 0; qh < 2; ++qh)
#pragma unroll
    for (int c = 0; c < 4; ++c)
      aq[qh][c] = *(const bf16x8*)(Qbase + (size_t)(qw0 + qh * 32 + l32) * HDIM +
                                   c * 16 + hi * 8);

  const f32x16 z16 = {};
  f32x16 oacc[2][2] = {};   // [qh][dh]
  float lsum[2] = {0.f, 0.f};   // [qh] softmax denominator partials

  const int srow = tid >> 3;           // 0..31
  const int scol = (tid & 7) * 8;      // key offset for staging
  const int keyg = scol >> 4;          // 16-key group
  const int todd = (scol >> 3) & 1;
  const int vkb = keyg * 16 + todd * 4;  // pi-permuted base for V staging
  const u16* Kg = K + (size_t)bh * S_LEN * HDIM + (size_t)srow * HDIM + scol;
  const u16* Vg = Vt + (size_t)bh * HDIM * S_LEN + (size_t)srow * S_LEN + scol;
  const float* mrow = maskL + (size_t)b * S_LEN;

  for (int kt = 0; kt < S_LEN; kt += 64) {
    bf16x8 kv0 = *(const bf16x8*)(Kg + (size_t)kt * HDIM);
    bf16x8 kv1 = *(const bf16x8*)(Kg + (size_t)(kt + 32) * HDIM);
    union { bf16x8 v; uint32_t u[4]; } vv0, vv1;
    vv0.v = *(const bf16x8*)(Vg + kt);
    vv1.v = *(const bf16x8*)(Vg + (size_t)32 * S_LEN + kt);
    __syncthreads();
    *(bf16x8*)(Ks + srow * 72 + scol) = kv0;
    *(bf16x8*)(Ks + (srow + 32) * 72 + scol) = kv1;
    // V with pi: keys {base..base+3} -> key' vkb, {base+4..7} -> key' vkb+8
    *(u32x2*)(Vs + srow * 72 + vkb) = (u32x2){vv0.u[0], vv0.u[1]};
    *(u32x2*)(Vs + srow * 72 + vkb + 8) = (u32x2){vv0.u[2], vv0.u[3]};
    *(u32x2*)(Vs + (srow + 32) * 72 + vkb) = (u32x2){vv1.u[0], vv1.u[1]};
    *(u32x2*)(Vs + (srow + 32) * 72 + vkb + 8) = (u32x2){vv1.u[2], vv1.u[3]};
    __syncthreads();

    uint32_t P[2][2][8];   // [T][qh][dword]
#pragma unroll
    for (int T = 0; T < 2; ++T) {
      bf16x8 kf[4];
#pragma unroll
      for (int c = 0; c < 4; ++c)
        kf[c] = *(const bf16x8*)(Ks + (T * 32 + l32) * 72 + c * 16 + hi * 8);
      f32x4 m4[4];
#pragma unroll
      for (int tq = 0; tq < 4; ++tq)
        m4[tq] = *(const f32x4*)(mrow + kt + T * 32 + tq * 8 + hi * 4);
#pragma unroll
      for (int qh = 0; qh < 2; ++qh) {
        f32x16 s = __builtin_amdgcn_mfma_f32_32x32x16_bf16(kf[0], aq[qh][0], z16, 0, 0, 0);
#pragma unroll
        for (int c = 1; c < 4; ++c)
          s = __builtin_amdgcn_mfma_f32_32x32x16_bf16(kf[c], aq[qh][c], s, 0, 0, 0);
        float lacc_t = 0.f;
#pragma unroll
        for (int tq = 0; tq < 4; ++tq) {
          float p0 = EXP2(fmaf(s[tq * 4 + 0], SC_L, m4[tq][0]));
          float p1 = EXP2(fmaf(s[tq * 4 + 1], SC_L, m4[tq][1]));
          float p2 = EXP2(fmaf(s[tq * 4 + 2], SC_L, m4[tq][2]));
          float p3 = EXP2(fmaf(s[tq * 4 + 3], SC_L, m4[tq][3]));
          P[T][qh][tq * 2] = packbf2(p0, p1);
          P[T][qh][tq * 2 + 1] = packbf2(p2, p3);
          lacc_t += (p0 + p1) + (p2 + p3);
        }
        lsum[qh] += lacc_t;
      }
    }

    // PV: A = in-register P fragments, B = pi-permuted V from LDS
#pragma unroll
    for (int c = 0; c < 4; ++c) {
      const int T = c >> 1, half = c & 1;
      bf16x8 vf[2];
#pragma unroll
      for (int dh = 0; dh < 2; ++dh)
        vf[dh] = *(const bf16x8*)(Vs + (dh * 32 + l32) * 72 + c * 16 + hi * 8);
#pragma unroll
      for (int qh = 0; qh < 2; ++qh) {
        union { uint32_t u[4]; bf16x8 v; } pf;
#pragma unroll
        for (int e = 0; e < 4; ++e) pf.u[e] = P[T][qh][half * 4 + e];
        oacc[qh][0] = __builtin_amdgcn_mfma_f32_32x32x16_bf16(pf.v, vf[0], oacc[qh][0], 0, 0, 0);
        oacc[qh][1] = __builtin_amdgcn_mfma_f32_32x32x16_bf16(pf.v, vf[1], oacc[qh][1], 0, 0, 0);
      }
    }
  }

  // merge hi-halves: lane's lsum covers a hi-dependent 16-key subset per tile;
  // partner lane (l32 same, hi flipped) covers the complement.
  float lt[2];
#pragma unroll
  for (int qh = 0; qh < 2; ++qh)
    lt[qh] = lsum[qh] + __shfl_xor(lsum[qh], 32);

  // epilogue: ctx [B,S,NH,HD]. l lives at lane q (QK^T col layout); oacc rows
  // need q = (reg&3)+8*(reg>>2)+4*hi -> bpermute.
#pragma unroll
  for (int qh = 0; qh < 2; ++qh) {
#pragma unroll
    for (int reg = 0; reg < 16; ++reg) {
      const int qloc = (reg & 3) + 8 * (reg >> 2) + 4 * hi;
      const int q = qw0 + qh * 32 + qloc;
      const float inv = 1.0f / __shfl(lt[qh], qloc);
      u16* cp = ctx + ((size_t)(b * S_LEN + q) * NHEAD + h) * HDIM;
      cp[l32] = f2bf(oacc[qh][0][reg] * inv);
      cp[32 + l32] = f2bf(oacc[qh][1][reg] * inv);
    }
  }
}

extern "C" void kernel_launch(void* const* d_in, const int* in_sizes, int n_in,
                              void* d_out, int out_size, void* d_ws, size_t ws_size,
                              hipStream_t stream) {
  const float* x = (const float*)d_in[0];
  const float* mask = (const float*)d_in[1];
  const float* Wq = (const float*)d_in[2];
  const float* bq = (const float*)d_in[3];
  const float* Wk = (const float*)d_in[4];
  const float* bk = (const float*)d_in[5];
  const float* Wv = (const float*)d_in[6];
  const float* bv = (const float*)d_in[7];
  const float* Wo = (const float*)d_in[8];
  const float* bo = (const float*)d_in[9];
  float* out = (float*)d_out;

  char* ws = (char*)d_ws;
  size_t off = 0;
  u16* xb = (u16*)(ws + off);    off += (size_t)MROWS * DMODEL * 2;
  u16* wall = (u16*)(ws + off);  off += (size_t)4 * DMODEL * DMODEL * 2;  // Wq,Wk,Wv,Wo transposed
  u16* Qh = (u16*)(ws + off);    off += (size_t)MROWS * DMODEL * 2;   // [B,NH,S,HD]
  u16* Kh = (u16*)(ws + off);    off += (size_t)MROWS * DMODEL * 2;
  u16* Vtb = (u16*)(ws + off);   off += (size_t)MROWS * DMODEL * 2;   // [B,NH,HD,S]
  u16* ctxb = (u16*)(ws + off);  off += (size_t)MROWS * DMODEL * 2;   // [B,S,D]
  float* mL = (float*)(ws + off); off += (size_t)BATCH * S_LEN * 4;
  (void)ws_size; (void)in_sizes; (void)n_in; (void)out_size;

  prep_kernel<<<dim3(NB_CVT + NB_W + BATCH * S_LEN / 256), dim3(256), 0, stream>>>(
      (const float4v*)x, (u32x2*)xb, Wq, Wk, Wv, Wo, wall, mask, mL);

  // fused QKV: N = 3072; V written transposed
  gemm128<0><<<dim3(MROWS / 128, 3 * DMODEL / 128), dim3(256), 0, stream>>>(
      xb, wall, bq, bk, bv, (void*)Qh, (void*)Kh, (void*)Vtb);

  attn8_kernel<<<dim3(S_LEN / 256, BATCH * NHEAD), dim3(256), 0, stream>>>(Qh, Kh, Vtb, mL, ctxb);

  gemm128<1><<<dim3(MROWS / 128, DMODEL / 128), dim3(256), 0, stream>>>(
      ctxb, wall + (size_t)3 * DMODEL * DMODEL, bo, bo, bo, (void*)out, (void*)out, (void*)out);
}